// Round 8
// baseline (81.349 us; speedup 1.0000x reference)
//
#include <hip/hip_runtime.h>

#define NSEQ 2048   // B*S
#define TT 30       // T
#define DIN 500
#define NLAYER 64

typedef _Float16 h8 __attribute__((ext_vector_type(8)));   // mfma operand type
typedef __fp16   q2 __attribute__((ext_vector_type(2)));   // cvt_pkrtz result type
typedef __fp16   q8 __attribute__((ext_vector_type(8)));
typedef float    f4 __attribute__((ext_vector_type(4)));

// fast transcendentals: v_exp_f32 / v_rcp_f32 (~1 ulp rel err; threshold is 2% rel)
__device__ __forceinline__ float fexp(float x) {
    return __builtin_amdgcn_exp2f(x * 1.4426950408889634f);
}
__device__ __forceinline__ float fsigmoid(float x) {
    return __builtin_amdgcn_rcpf(1.0f + fexp(-x));
}
__device__ __forceinline__ float ftanh_(float x) {
    return fmaf(-2.0f, __builtin_amdgcn_rcpf(1.0f + fexp(2.0f * x)), 1.0f);
}
__device__ __forceinline__ float rdlane(float v, int l) {
    return __builtin_bit_cast(float, __builtin_amdgcn_readlane(__builtin_bit_cast(int, v), l));
}
template <int CTRL>
__device__ __forceinline__ float dppmv(float v) {
    return __builtin_bit_cast(float, __builtin_amdgcn_update_dpp(
        0, __builtin_bit_cast(int, v), CTRL, 0xF, 0xF, false));
}
#define DPP_SHR1 0x138  // wave_shr:1 (lane l <- lane l-1)

// pack 8 floats (as 4 q2 halves) into an mfma h8 operand
__device__ __forceinline__ h8 pack8(q2 p0, q2 p1, q2 p2, q2 p3) {
    q8 r;
    r[0] = p0.x; r[1] = p0.y; r[2] = p1.x; r[3] = p1.y;
    r[4] = p2.x; r[5] = p2.y; r[6] = p3.x; r[7] = p3.y;
    return __builtin_bit_cast(h8, r);
}

// global->LDS direct copy, 16 B/lane; LDS dest = wave-uniform base (+lane*16 implicit)
__device__ __forceinline__ void gld16(const void* g, void* l) {
    __builtin_amdgcn_global_load_lds(
        (const __attribute__((address_space(1))) void*)g,
        (__attribute__((address_space(3))) void*)l, 16, 0, 0);
}

// v8b (v8 + type fix + boundary fix): phase 1 on the MATRIX pipe. v5
// (guaranteed 12KB/wave in flight) and v7 (50% occupancy) both nulled, and
// cache-resident replays run at the same speed as HBM-fed ones => the kernel
// is ISSUE-bound, not memory-bound. Phase 1 per seq was ~2850 wave-instrs
// (48-instr DPP reduction tax per t); as C[30x4] = A[30x500]xW^T it is one
// small GEMM: 32x mfma_f32_16x16x32_f16 per seq (k split 2x across wave
// pairs), ~480 wave-instrs total, no DPP chains. f16 inputs: ~0.1% output
// err vs 2% tolerance; fp32 accumulate.
// Layouts: C/D col=lane&15,row=(lane>>4)*4+reg [m89-verified]; A/B
// row/col=lane&15, k=8*(lane>>4)+e [m162-consistent].
// Boundary: x staged behind a 4-float ZERO pad; fb clamped to -4 so the
// (t=29,kh=1,s=7,q=2) case reads the true xs[3..0] words and every masked
// k>=500 element multiplies a finite zero (never 0x NaN).
__global__ __launch_bounds__(256, 2) void fused_lstm(
    const float* __restrict__ x,       // (NSEQ, TT*DIN)
    const float* __restrict__ w_ih0,   // (4, DIN)
    const float* __restrict__ w_hh0,   // (4,1)
    const float* __restrict__ b_ih0,   // (4)
    const float* __restrict__ b_hh0,   // (4)
    const float* __restrict__ w_ih,    // (63,4,1)
    const float* __restrict__ w_hh,    // (63,4,1)
    const float* __restrict__ b_ih,    // (63,4)
    const float* __restrict__ b_hh,    // (63,4)
    float* __restrict__ out)           // (NSEQ, TT)
{
    __shared__ __align__(16) float xs_raw[4 + 59 * 256];  // 4-float zero pad + x row
    __shared__ __align__(16) float preA[128], preB[128];  // k-half partial C

    float* const xsp = xs_raw + 4;     // staged x row; xsp[-4..-1] = zero pad

    const int tid  = threadIdx.x;
    const int lane = tid & 63;
    const int w    = tid >> 6;
    const int n    = blockIdx.x;       // one sequence per block

    const int mt = w & 1;              // M-tile: rows t = 16*mt + 0..15
    const int kh = w >> 1;             // k-half: k = 256*kh + 0..255

    // ---- B-frag preload (global, issued first; reused for all k-steps) ----
    // B[k][g] = w_ih0[g][k]; lane: g = lane&15 (valid g<4), k = kb + 8q + e.
    const int bg = lane & 15;
    const int q  = lane >> 4;
    const int nrow = (bg < 4) ? bg : 0;            // clamp OOB gate rows
    h8 Bfr[8];
#pragma unroll
    for (int s = 0; s < 8; ++s) {
        const int k0 = 256 * kh + 32 * s + 8 * q;
        const float* wr = w_ih0 + nrow * 500;
        const float4 F0 = *(const float4*)(wr + ((k0     <= 496) ? k0     : 496));
        const float4 F1 = *(const float4*)(wr + ((k0 + 4 <= 496) ? k0 + 4 : 496));
        const float e0 = (k0 + 0 < 500) ? F0.x : 0.f;
        const float e1 = (k0 + 1 < 500) ? F0.y : 0.f;
        const float e2 = (k0 + 2 < 500) ? F0.z : 0.f;
        const float e3 = (k0 + 3 < 500) ? F0.w : 0.f;
        const float e4 = (k0 + 4 < 500) ? F1.x : 0.f;
        const float e5 = (k0 + 5 < 500) ? F1.y : 0.f;
        const float e6 = (k0 + 6 < 500) ? F1.z : 0.f;
        const float e7 = (k0 + 7 < 500) ? F1.w : 0.f;
        Bfr[s] = pack8(__builtin_amdgcn_cvt_pkrtz(e0, e1),
                       __builtin_amdgcn_cvt_pkrtz(e2, e3),
                       __builtin_amdgcn_cvt_pkrtz(e4, e5),
                       __builtin_amdgcn_cvt_pkrtz(e6, e7));
    }

    // ---- stage x row to LDS (59 chunks x 1024 B, coalesced, zero VGPR) ----
    const float4* __restrict__ xq4 = (const float4*)(x + (size_t)n * (TT * DIN));
    for (int i = 0; i < 15; ++i) {
        const int j = w * 15 + i;                   // wave-uniform chunk id
        if (j >= 59) break;
        const int sq = 64 * j + lane;               // quad index, max valid 3749
        gld16(xq4 + ((sq <= 3749) ? sq : 3749), (char*)xsp + j * 1024);
    }
    if (tid < 4) xs_raw[tid] = 0.f;                 // zero the front pad
    asm volatile("s_waitcnt vmcnt(0)" ::: "memory");
    __syncthreads();   // xsp[] complete

    // ---- 8 k-steps of mfma: A from LDS (reversed), acc in fp32 ----
    // A[t][k] = xrev[t][k] = xsp[14999 - t*500 - k]; elem e at xsp[fb+7-e].
    // fb stays 16B-aligned (all terms ==0 mod 4); clamp at -4: the only
    // valid-t negative case (t=29,kh=1,s=7,q=2, k=496..499) then reads
    // exactly xsp[3..0]; deeper negatives occur only for k>=504 or pad rows
    // (B=0 / D discarded), and land in the finite zero pad.
    const int am = lane & 15;                       // A row within tile
    const int at = 16 * mt + am;                    // timestep (30,31 = pad)
    f4 acc = {0.f, 0.f, 0.f, 0.f};
    const int fb_start = 14992 - at * 500 - 256 * kh - 8 * q;
#pragma unroll
    for (int s = 0; s < 8; ++s) {
        int fb = fb_start - 32 * s;
        if (fb < -4) fb = -4;
        const float4 M0 = *(const float4*)&xsp[fb];
        const float4 M1 = *(const float4*)&xsp[fb + 4];
        const h8 a = pack8(__builtin_amdgcn_cvt_pkrtz(M1.w, M1.z),   // elems 0,1
                           __builtin_amdgcn_cvt_pkrtz(M1.y, M1.x),   // elems 2,3
                           __builtin_amdgcn_cvt_pkrtz(M0.w, M0.z),   // elems 4,5
                           __builtin_amdgcn_cvt_pkrtz(M0.y, M0.x));  // elems 6,7
        acc = __builtin_amdgcn_mfma_f32_16x16x32_f16(a, Bfr[s], acc, 0, 0, 0);
    }

    // ---- D-write: lane holds D[4*q + r][bg]; t = 16*mt + 4*q + r ----
    float* const dst = (kh == 0) ? preA : preB;
    if (bg < 4) {
#pragma unroll
        for (int r = 0; r < 4; ++r) {
            const int t = 16 * mt + 4 * q + r;
            if (t < TT) dst[t * 4 + bg] = acc[r];
        }
    }
    __syncthreads();   // pre partials complete

    if (w != 0) return;   // waves 1-3 free their slots

    // ---- phase-2 parameters (verbatim v7) ----
    const int l = (lane == 0) ? 0 : (lane - 1);
    const float4 wihv  = *(const float4*)(w_ih + l * 4);
    const float4 whhv  = *(const float4*)(w_hh + l * 4);
    const float4 bihv  = *(const float4*)(b_ih + l * 4);
    const float4 bhhv  = *(const float4*)(b_hh + l * 4);
    const float4 whh0v = *(const float4*)(w_hh0);
    const float4 bi0v  = *(const float4*)(b_ih0);
    const float4 bh0v  = *(const float4*)(b_hh0);

    float wih0, wih1, wih2, wih3, whh0, whh1, whh2, whh3;
    float bia0, bia1, bia2, bia3;
    if (lane == 0) {
        wih0 = wih1 = wih2 = wih3 = 0.f;
        bia0 = bia1 = bia2 = bia3 = 0.f;
        whh0 = whh0v.x; whh1 = whh0v.y; whh2 = whh0v.z; whh3 = whh0v.w;
    } else {
        wih0 = wihv.x; wih1 = wihv.y; wih2 = wihv.z; wih3 = wihv.w;
        whh0 = whhv.x; whh1 = whhv.y; whh2 = whhv.z; whh3 = whhv.w;
        bia0 = bihv.x + bhhv.x; bia1 = bihv.y + bhhv.y;
        bia2 = bihv.z + bhhv.z; bia3 = bihv.w + bhhv.w;
    }
    float pg0 = 0.f, pg1 = 0.f, pg2 = 0.f, pg3 = 0.f;
    if (lane < TT) {
        const float4 qa = *(const float4*)&preA[lane * 4];
        const float4 qb = *(const float4*)&preB[lane * 4];
        pg0 = qa.x + qb.x + bi0v.x + bh0v.x;
        pg1 = qa.y + qb.y + bi0v.y + bh0v.y;
        pg2 = qa.z + qb.z + bi0v.z + bh0v.z;
        pg3 = qa.w + qb.w + bi0v.w + bh0v.w;
    }

    // ---- phase 2: (layer,time) wavefront, lane = layer (validated v2-v7) ----
    float h = 0.f, c = 0.f;
    for (int k = 0; k < NLAYER + TT - 1; ++k) {
        const float h_in = dppmv<DPP_SHR1>(h);
        const int t = k - lane;
        const bool active = (t >= 0) && (t < TT);

        float g0, g1, g2, g3;
        if (lane == 0) {
            g0 = g1 = g2 = g3 = 0.f;
        } else {
            g0 = fmaf(h_in, wih0, bia0);
            g1 = fmaf(h_in, wih1, bia1);
            g2 = fmaf(h_in, wih2, bia2);
            g3 = fmaf(h_in, wih3, bia3);
        }
        if (k < TT) {
            const float p0 = rdlane(pg0, k);
            const float p1 = rdlane(pg1, k);
            const float p2 = rdlane(pg2, k);
            const float p3 = rdlane(pg3, k);
            if (lane == 0) { g0 = p0; g1 = p1; g2 = p2; g3 = p3; }
        }
        g0 = fmaf(h, whh0, g0);
        g1 = fmaf(h, whh1, g1);
        g2 = fmaf(h, whh2, g2);
        g3 = fmaf(h, whh3, g3);

        const float ig = fsigmoid(g0);
        const float fg = fsigmoid(g1);
        const float gg = ftanh_(g2);
        const float og = fsigmoid(g3);
        const float cn = fmaf(fg, c, ig * gg);
        const float hn = og * ftanh_(cn);

        if (active) { c = cn; h = hn; }
        if (lane == 63 && active) out[(size_t)n * TT + t] = hn;
    }
}

extern "C" void kernel_launch(void* const* d_in, const int* in_sizes, int n_in,
                              void* d_out, int out_size, void* d_ws, size_t ws_size,
                              hipStream_t stream) {
    const float* x     = (const float*)d_in[0];
    const float* w_ih0 = (const float*)d_in[1];
    const float* w_hh0 = (const float*)d_in[2];
    const float* b_ih0 = (const float*)d_in[3];
    const float* b_hh0 = (const float*)d_in[4];
    const float* w_ih  = (const float*)d_in[5];
    const float* w_hh  = (const float*)d_in[6];
    const float* b_ih  = (const float*)d_in[7];
    const float* b_hh  = (const float*)d_in[8];
    float* out = (float*)d_out;

    fused_lstm<<<NSEQ, 256, 0, stream>>>(x, w_ih0, w_hh0, b_ih0, b_hh0,
                                         w_ih, w_hh, b_ih, b_hh, out);
}

// Round 10
// 50.371 us; speedup vs baseline: 1.6150x; 1.6150x over previous
//
#include <hip/hip_runtime.h>

#define NSEQ 2048   // B*S
#define TT 30       // T
#define DIN 500
#define NLAYER 64

typedef float v4f __attribute__((ext_vector_type(4)));   // native vec for nt builtin

// fast transcendentals: v_exp_f32 / v_rcp_f32 (~1 ulp rel err; threshold is 2% rel)
__device__ __forceinline__ float fexp(float x) {
    return __builtin_amdgcn_exp2f(x * 1.4426950408889634f);
}
__device__ __forceinline__ float fsigmoid(float x) {
    return __builtin_amdgcn_rcpf(1.0f + fexp(-x));
}
__device__ __forceinline__ float ftanh_(float x) {
    return fmaf(-2.0f, __builtin_amdgcn_rcpf(1.0f + fexp(2.0f * x)), 1.0f);
}
__device__ __forceinline__ float rdlane(float v, int l) {
    return __builtin_bit_cast(float, __builtin_amdgcn_readlane(__builtin_bit_cast(int, v), l));
}
template <int CTRL>
__device__ __forceinline__ float dppmv(float v) {
    return __builtin_bit_cast(float, __builtin_amdgcn_update_dpp(
        0, __builtin_bit_cast(int, v), CTRL, 0xF, 0xF, false));
}
#define DPP_ROW_SHR1   0x111
#define DPP_ROW_SHR2   0x112
#define DPP_ROW_SHR4   0x114
#define DPP_ROW_SHR8   0x118
#define DPP_BCAST15    0x142
#define DPP_BCAST31    0x143
#define DPP_SHR1       0x138  // wave_shr:1 (lane l <- lane l-1)

// x float4 pairs with chunk-reversed weight float4: component c <-> component 3-c
__device__ __forceinline__ float dot4rev(const float4 xv, const float4 wv, float acc) {
    acc = fmaf(xv.x, wv.w, acc);
    acc = fmaf(xv.y, wv.z, acc);
    acc = fmaf(xv.z, wv.y, acc);
    acc = fmaf(xv.w, wv.x, acc);
    return acc;
}
// 64-lane sum; total lands in lane 63 (validated v4-v7)
__device__ __forceinline__ float red64(float a) {
    a += dppmv<DPP_ROW_SHR1>(a);
    a += dppmv<DPP_ROW_SHR2>(a);
    a += dppmv<DPP_ROW_SHR4>(a);
    a += dppmv<DPP_ROW_SHR8>(a);
    a += dppmv<DPP_BCAST15>(a);
    a += dppmv<DPP_BCAST31>(a);
    return a;
}
// non-temporal (streaming) load: nt policy, no L1 allocation.
// builtin requires a native vector type, not HIP_vector_type.
__device__ __forceinline__ float4 ntl(const float4* p) {
    v4f r = __builtin_nontemporal_load((const v4f*)p);
    return __builtin_bit_cast(float4, r);
}

// v9b (v9 + type fix): NON-TEMPORAL x stream. 9-round evidence: dur ~42us
// invariant to per-wave depth (v5 GLL ring: null), occupancy (v7 50%: null),
// instr count (v8b mfma 6x cut: worse), and data source (cache-resident
// replays = HBM replays). Per-CU read rate ~4.7 B/cyc matches an L1
// miss-concurrency ceiling (~32 lines x 128B / ~900cy). v9 attacks exactly
// that: x loads use nt (no L1 allocation); layout is the v4-validated
// slice-dot (fully distinct 1KB per load instr, nothing relies on L1 dedup);
// 2-t unroll in named registers (16 VGPR). Shell = v2 (one wave/seq fused).
__global__ __launch_bounds__(256, 2) void fused_lstm(
    const float* __restrict__ x,       // (NSEQ, TT*DIN)
    const float* __restrict__ w_ih0,   // (4, DIN)
    const float* __restrict__ w_hh0,   // (4,1)
    const float* __restrict__ b_ih0,   // (4)
    const float* __restrict__ b_hh0,   // (4)
    const float* __restrict__ w_ih,    // (63,4,1)
    const float* __restrict__ w_hh,    // (63,4,1)
    const float* __restrict__ b_ih,    // (63,4)
    const float* __restrict__ b_hh,    // (63,4)
    float* __restrict__ out)           // (NSEQ, TT)
{
    __shared__ float pre[4][TT * 4];   // per-wave slice, 480 B each

    const int tid  = threadIdx.x;
    const int lane = tid & 63;
    const int w    = tid >> 6;
    const int n    = blockIdx.x * 4 + w;   // this wave's sequence
    float* __restrict__ prew = pre[w];

    // ---- slice weights (validated v4-v7): lane l pairs x-quads {l, 64+l}
    // with reversed w-quads {124-l, 60-l}; 8 float4 = 32 VGPR ----
    const float4* __restrict__ w4 = (const float4*)w_ih0;   // 500 quads, row g*125
    const float4 z4 = make_float4(0.f, 0.f, 0.f, 0.f);
    float4 wq0[4], wq1[4];
#pragma unroll
    for (int g = 0; g < 4; ++g) {
        wq0[g] = w4[g * 125 + (124 - lane)];
        wq1[g] = (lane < 61) ? w4[g * 125 + (60 - lane)] : z4;
    }

    const float4* __restrict__ xq = (const float4*)(x + (size_t)n * (TT * DIN));
    const int xbi = (lane < 61) ? (64 + lane) : 124;   // clamped dup, weight 0

    // ---- phase 1: 30 t, 2-t unroll, nt loads (4 x 1KB in flight/wave) ----
#pragma unroll 3
    for (int t = 0; t < TT; t += 2) {
        const float4* __restrict__ p0 = xq + (TT - 1 - t) * 125;
        const float4* __restrict__ p1 = xq + (TT - 2 - t) * 125;
        const float4 xa0 = ntl(p0 + lane);
        const float4 xb0 = ntl(p0 + xbi);
        const float4 xa1 = ntl(p1 + lane);
        const float4 xb1 = ntl(p1 + xbi);

        float a0 = dot4rev(xa0, wq0[0], 0.f); a0 = dot4rev(xb0, wq1[0], a0);
        float a1 = dot4rev(xa0, wq0[1], 0.f); a1 = dot4rev(xb0, wq1[1], a1);
        float a2 = dot4rev(xa0, wq0[2], 0.f); a2 = dot4rev(xb0, wq1[2], a2);
        float a3 = dot4rev(xa0, wq0[3], 0.f); a3 = dot4rev(xb0, wq1[3], a3);
        a0 = red64(a0); a1 = red64(a1); a2 = red64(a2); a3 = red64(a3);
        if (lane == 63)
            *(float4*)&prew[t * 4] = make_float4(a0, a1, a2, a3);

        float b0 = dot4rev(xa1, wq0[0], 0.f); b0 = dot4rev(xb1, wq1[0], b0);
        float b1 = dot4rev(xa1, wq0[1], 0.f); b1 = dot4rev(xb1, wq1[1], b1);
        float b2 = dot4rev(xa1, wq0[2], 0.f); b2 = dot4rev(xb1, wq1[2], b2);
        float b3 = dot4rev(xa1, wq0[3], 0.f); b3 = dot4rev(xb1, wq1[3], b3);
        b0 = red64(b0); b1 = red64(b1); b2 = red64(b2); b3 = red64(b3);
        if (lane == 63)
            *(float4*)&prew[(t + 1) * 4] = make_float4(b0, b1, b2, b3);
    }
    // same-wave DS ops retire in order; drain lgkm so reads below see writes
    asm volatile("s_waitcnt lgkmcnt(0)" ::: "memory");

    // ---- phase-2 parameters (loaded now; L2-hot, trivial latency) ----
    const int l = (lane == 0) ? 0 : (lane - 1);
    const float4 wihv  = *(const float4*)(w_ih + l * 4);
    const float4 whhv  = *(const float4*)(w_hh + l * 4);
    const float4 bihv  = *(const float4*)(b_ih + l * 4);
    const float4 bhhv  = *(const float4*)(b_hh + l * 4);
    const float4 whh0v = *(const float4*)(w_hh0);
    const float4 bi0v  = *(const float4*)(b_ih0);
    const float4 bh0v  = *(const float4*)(b_hh0);

    float wih0, wih1, wih2, wih3, whh0, whh1, whh2, whh3;
    float bia0, bia1, bia2, bia3;
    if (lane == 0) {
        wih0 = wih1 = wih2 = wih3 = 0.f;
        bia0 = bia1 = bia2 = bia3 = 0.f;
        whh0 = whh0v.x; whh1 = whh0v.y; whh2 = whh0v.z; whh3 = whh0v.w;
    } else {
        wih0 = wihv.x; wih1 = wihv.y; wih2 = wihv.z; wih3 = wihv.w;
        whh0 = whhv.x; whh1 = whhv.y; whh2 = whhv.z; whh3 = whhv.w;
        bia0 = bihv.x + bhhv.x; bia1 = bihv.y + bhhv.y;
        bia2 = bihv.z + bhhv.z; bia3 = bihv.w + bhhv.w;
    }
    float pg0 = 0.f, pg1 = 0.f, pg2 = 0.f, pg3 = 0.f;
    if (lane < TT) {
        const float4 q = *(const float4*)&prew[lane * 4];
        pg0 = q.x + bi0v.x + bh0v.x;
        pg1 = q.y + bi0v.y + bh0v.y;
        pg2 = q.z + bi0v.z + bh0v.z;
        pg3 = q.w + bi0v.w + bh0v.w;
    }

    // ---- phase 2: (layer,time) wavefront, lane = layer (validated v2-v8) ----
    float h = 0.f, c = 0.f;
    for (int k = 0; k < NLAYER + TT - 1; ++k) {
        const float h_in = dppmv<DPP_SHR1>(h);
        const int t = k - lane;
        const bool active = (t >= 0) && (t < TT);

        float g0, g1, g2, g3;
        if (lane == 0) {
            g0 = g1 = g2 = g3 = 0.f;
        } else {
            g0 = fmaf(h_in, wih0, bia0);
            g1 = fmaf(h_in, wih1, bia1);
            g2 = fmaf(h_in, wih2, bia2);
            g3 = fmaf(h_in, wih3, bia3);
        }
        if (k < TT) {
            const float p0 = rdlane(pg0, k);
            const float p1 = rdlane(pg1, k);
            const float p2 = rdlane(pg2, k);
            const float p3 = rdlane(pg3, k);
            if (lane == 0) { g0 = p0; g1 = p1; g2 = p2; g3 = p3; }
        }
        g0 = fmaf(h, whh0, g0);
        g1 = fmaf(h, whh1, g1);
        g2 = fmaf(h, whh2, g2);
        g3 = fmaf(h, whh3, g3);

        const float ig = fsigmoid(g0);
        const float fg = fsigmoid(g1);
        const float gg = ftanh_(g2);
        const float og = fsigmoid(g3);
        const float cn = fmaf(fg, c, ig * gg);
        const float hn = og * ftanh_(cn);

        if (active) { c = cn; h = hn; }
        if (lane == 63 && active) out[(size_t)n * TT + t] = hn;
    }
}

extern "C" void kernel_launch(void* const* d_in, const int* in_sizes, int n_in,
                              void* d_out, int out_size, void* d_ws, size_t ws_size,
                              hipStream_t stream) {
    const float* x     = (const float*)d_in[0];
    const float* w_ih0 = (const float*)d_in[1];
    const float* w_hh0 = (const float*)d_in[2];
    const float* b_ih0 = (const float*)d_in[3];
    const float* b_hh0 = (const float*)d_in[4];
    const float* w_ih  = (const float*)d_in[5];
    const float* w_hh  = (const float*)d_in[6];
    const float* b_ih  = (const float*)d_in[7];
    const float* b_hh  = (const float*)d_in[8];
    float* out = (float*)d_out;

    fused_lstm<<<NSEQ / 4, 256, 0, stream>>>(x, w_ih0, w_hh0, b_ih0, b_hh0,
                                             w_ih, w_hh, b_ih, b_hh, out);
}